// Round 8
// baseline (313.534 us; speedup 1.0000x reference)
//
#include <hip/hip_runtime.h>
#include <hip/hip_bf16.h>

// ============================================================================
// GAT 2-layer forward, round 22.
// r21 post-mortem: per-node arena scatter REGRESSED (271us): WRITE_SIZE 112MB
// vs 36MB useful — random 4B writes across 19.6MB thrash 4MB/XCD L2s (RFO +
// dirty-evict per edge). Rule: bucketed write-combining is mandatory; revert
// to r19's two-phase CSR. r19 accounting: seg kernels at fill ceiling (~95us),
// part+bucket+gemm ~60us, ~60-80us = 4-5 dispatch boundaries @ ~15-18us.
// Change vs r19 (one variable): merge k_pg+k_bg into ONE dispatch k_pgb via a
// one-directional flag: part blocks (bids 0..390) release-add `done`; bucket
// blocks (last 196 bids) acquire-spin for done==NT then run. Producers are
// earlier bids and never wait -> deadlock-free. NOT a grid.sync (r20's 150us
// rendezvous); single flag, one direction. gemm1/wExt ride along untouched.
// 4 dispatches: memset -> k_pgb -> seg1f -> seg2f. Bodies byte-identical r19.
// Facts: fp32 in/out, int32 edge_index, N=100000 E=1600000, bf16 h.
// ============================================================================

typedef __hip_bfloat16 bf16;
typedef unsigned short ushort;
typedef unsigned char uchar;
typedef __attribute__((ext_vector_type(8))) short short8;
typedef __attribute__((ext_vector_type(4))) float f32x4;

#define NN 100000
#define EE 1600000
#define BKB 9
#define BKN (1 << BKB)
#define NBK ((NN + BKN - 1) >> BKB)   // 196
#define CAP 10240                     // arena slots per bucket (max ~8.5K)
#define TILE 4096
#define EPT 16
#define NT ((EE + TILE - 1) / TILE)   // 391 part blocks
#define GT 782                        // gemm1 tile-pattern anchor (unchanged)
#define BN 16                         // nodes per seg group
#define CHE 512                       // max edges/group: mean 256, +16 sigma
#define NGRP (NN / BN)                // 6250 seg groups
#define PGB_GRID (NT + GT + 1 + NBK)  // 1370

__device__ __forceinline__ float relu_np(float v) { return (v < 0.f) ? 0.f : v; }
__device__ __forceinline__ float lrelu(float v) { return v > 0.f ? v : 0.2f * v; }
__device__ __forceinline__ ushort f2bf(float f) {
    __hip_bfloat16 h = __float2bfloat16(f);
    return *reinterpret_cast<ushort*>(&h);
}
__device__ __forceinline__ float bf2f(ushort u) {
    unsigned int x = ((unsigned int)u) << 16;
    return __uint_as_float(x);
}
__device__ __forceinline__ int load_acq(const int* p) {
    return __hip_atomic_load(p, __ATOMIC_ACQUIRE, __HIP_MEMORY_SCOPE_AGENT);
}

// ---- LDS union for the fused front kernel ----------------------------------
struct SmemG { ushort wB[64 * 128]; ushort wE[16 * 128]; };
struct SmemP { int lh[NBK]; int lbase[NBK]; };
struct SmemB { int hist[BKN]; int sP[256]; };
union __align__(16) SmemF { SmemG g; SmemP p; SmemB b; };

// ---- part body: bucketed arena partition (byte-identical to r19) -----------
__device__ __forceinline__ void part_body(
    int u, SmemP& sp, const int* __restrict__ src, const int* __restrict__ dst,
    int* __restrict__ gcur, int* __restrict__ pairs)
{
    const int tid = threadIdx.x;
    for (int i = tid; i < NBK; i += 256) sp.lh[i] = 0;
    __syncthreads();
    const int e0 = u * TILE;
    int pk[EPT], bk[EPT], rv[EPT];
    #pragma unroll
    for (int j = 0; j < EPT; ++j) {
        int e = e0 + j * 256 + tid;
        if (e < EE) {
            int d = dst[e];
            bk[j] = d >> BKB;
            pk[j] = src[e] | ((d & (BKN - 1)) << 17);
            rv[j] = atomicAdd(&sp.lh[bk[j]], 1);
        }
    }
    __syncthreads();
    for (int i = tid; i < NBK; i += 256)
        sp.lbase[i] = sp.lh[i] ? atomicAdd(&gcur[i], sp.lh[i]) : 0;
    __syncthreads();
    #pragma unroll
    for (int j = 0; j < EPT; ++j) {
        int e = e0 + j * 256 + tid;
        if (e < EE)
            pairs[(size_t)bk[j] * CAP + sp.lbase[bk[j]] + rv[j]] = pk[j];
    }
}

// ---- gemm1 body (byte-identical tile pattern) ------------------------------
__device__ __forceinline__ void gemm1_body(
    int gb, SmemG& sg,
    const float* __restrict__ x, const float* __restrict__ W1,
    const float* __restrict__ aS, const float* __restrict__ aD,
    ushort* __restrict__ h1, float* __restrict__ as1, float* __restrict__ ad1)
{
    const int tid = threadIdx.x;
    for (int i = tid; i < 128 * 64; i += 256) {
        int k = i >> 6, n = i & 63;
        sg.wB[n * 128 + k] = f2bf(W1[i]);
    }
    for (int i = tid; i < 128 * 16; i += 256) {
        int k = i >> 4, j = i & 15;
        float v = 0.f;
        if (j < 8) {
            int h = j & 3;
            const float* av = (j < 4) ? aS : aD;
            for (int c = 0; c < 16; ++c)
                v = fmaf(W1[k * 64 + h * 16 + c], av[h * 16 + c], v);
        }
        sg.wE[j * 128 + k] = f2bf(v);
    }
    __syncthreads();
    const int w = tid >> 6, lane = tid & 63;
    const int m = lane & 15, quad = lane >> 4;
    const int ntiles = NN >> 4;
    for (int tile = gb * 4 + w; tile < ntiles; tile += GT * 4) {
        const int row0 = tile << 4;
        f32x4 acc[4] = {f32x4{0,0,0,0}, f32x4{0,0,0,0},
                        f32x4{0,0,0,0}, f32x4{0,0,0,0}};
        f32x4 acc5 = {0, 0, 0, 0};
        const float* xp = x + (size_t)(row0 + m) * 128 + quad * 8;
        #pragma unroll
        for (int ks = 0; ks < 128; ks += 32) {
            f32x4 x0 = *(const f32x4*)(xp + ks);
            f32x4 x1 = *(const f32x4*)(xp + ks + 4);
            short8 a;
            #pragma unroll
            for (int j = 0; j < 4; ++j) a[j] = (short)f2bf(x0[j]);
            #pragma unroll
            for (int j = 0; j < 4; ++j) a[4 + j] = (short)f2bf(x1[j]);
            #pragma unroll
            for (int t = 0; t < 4; ++t) {
                short8 b = *(const short8*)&sg.wB[(t * 16 + m) * 128 + ks + quad * 8];
                acc[t] = __builtin_amdgcn_mfma_f32_16x16x32_bf16(a, b, acc[t], 0, 0, 0);
            }
            short8 b5 = *(const short8*)&sg.wE[m * 128 + ks + quad * 8];
            acc5 = __builtin_amdgcn_mfma_f32_16x16x32_bf16(a, b5, acc5, 0, 0, 0);
        }
        #pragma unroll
        for (int t = 0; t < 4; ++t)
            #pragma unroll
            for (int r = 0; r < 4; ++r)
                h1[(size_t)(row0 + quad * 4 + r) * 64 + t * 16 + m] = f2bf(acc[t][r]);
        #pragma unroll
        for (int r = 0; r < 4; ++r) {
            int row = row0 + quad * 4 + r;
            if (m < 4) as1[row * 4 + m] = acc5[r];
            else if (m < 8) ad1[row * 4 + (m - 4)] = acc5[r];
        }
    }
}

// ---- bucket body: hist + scan -> CSR (byte-identical to r19) ---------------
__device__ __forceinline__ void bucket_body(
    int b, SmemB& sb, const int* __restrict__ gcur, const int* __restrict__ pairs,
    int* __restrict__ row_ptr, uchar* __restrict__ rcnt, int* __restrict__ col)
{
    const int n0 = b << BKB;
    const int tid = threadIdx.x;
    const int base = b * CAP, endE = base + load_acq(&gcur[b]);
    for (int i = tid; i < BKN; i += 256) sb.hist[i] = 0;
    __syncthreads();
    for (int i = base + tid; i < endE; i += 256)
        atomicAdd(&sb.hist[pairs[i] >> 17], 1);
    __syncthreads();
    int a0 = sb.hist[2 * tid], a1 = sb.hist[2 * tid + 1];
    int tot = a0 + a1;
    sb.sP[tid] = tot;
    __syncthreads();
    for (int off = 1; off < 256; off <<= 1) {
        int t = (tid >= off) ? sb.sP[tid - off] : 0;
        __syncthreads();
        sb.sP[tid] += t;
        __syncthreads();
    }
    const int excl = sb.sP[tid] - tot;
    const int c0 = base + excl;
    sb.hist[2 * tid] = c0;
    sb.hist[2 * tid + 1] = c0 + a0;
    if (n0 + 2 * tid < NN) {
        row_ptr[n0 + 2 * tid] = c0;
        rcnt[n0 + 2 * tid] = (uchar)a0;
    }
    if (n0 + 2 * tid + 1 < NN) {
        row_ptr[n0 + 2 * tid + 1] = c0 + a0;
        rcnt[n0 + 2 * tid + 1] = (uchar)a1;
    }
    __syncthreads();
    for (int i = base + tid; i < endE; i += 256) {
        int pr = pairs[i];
        int p = atomicAdd(&sb.hist[pr >> 17], 1);
        col[p] = pr & 0x1FFFF;
    }
}

// ---- fused front: part || gemm1 || wExt, then bucket (flag-ordered) --------
__global__ __launch_bounds__(256) void k_pgb(
    const int* __restrict__ src, const int* __restrict__ dst,
    int* __restrict__ gcur, int* __restrict__ done, int* __restrict__ pairs,
    const float* __restrict__ x, const float* __restrict__ W1,
    const float* __restrict__ aS1, const float* __restrict__ aD1,
    ushort* __restrict__ h1, float* __restrict__ as1, float* __restrict__ ad1,
    const float* __restrict__ W2, const float* __restrict__ aS2,
    const float* __restrict__ aD2, ushort* __restrict__ wExt,
    int* __restrict__ row_ptr, uchar* __restrict__ rcnt, int* __restrict__ col)
{
    __shared__ SmemF sm;
    const int bid = blockIdx.x;
    const int tid = threadIdx.x;

    if (bid < NT) {
        part_body(bid, sm.p, src, dst, gcur, pairs);
        __syncthreads();                       // all stores drained (vmcnt)
        if (tid == 0) {
            __threadfence();                   // publish pairs/gcur agent-wide
            __hip_atomic_fetch_add(done, 1, __ATOMIC_RELEASE,
                                   __HIP_MEMORY_SCOPE_AGENT);
        }
    } else if (bid < NT + GT) {
        gemm1_body(bid - NT, sm.g, x, W1, aS1, aD1, h1, as1, ad1);
    } else if (bid == NT + GT) {
        // wExt^T bf16 [80][64]: n<64: W2 col n; 64: W2@aS2; 65: W2@aD2
        for (int i = tid; i < 80 * 64; i += 256) {
            int n = i >> 6, k = i & 63;
            float v = 0.f;
            if (n < 64) {
                v = W2[k * 64 + n];
            } else if (n == 64) {
                for (int c = 0; c < 64; ++c) v = fmaf(W2[k * 64 + c], aS2[c], v);
            } else if (n == 65) {
                for (int c = 0; c < 64; ++c) v = fmaf(W2[k * 64 + c], aD2[c], v);
            }
            wExt[i] = f2bf(v);
        }
    } else {
        // bucket: wait for all part blocks (one-directional, deadlock-free:
        // producers are earlier bids and never wait on anyone)
        if (tid == 0) {
            while (load_acq(done) < NT) __builtin_amdgcn_s_sleep(16);
        }
        __syncthreads();
        __threadfence();                       // invalidate stale cached lines
        bucket_body(bid - (NT + GT + 1), sm.b, gcur, pairs, row_ptr, rcnt, col);
    }
}

// ---------------- layer-1 seg aggregation + fused layer-2 GEMM ---------------
// (byte-identical to r19) 16 nodes/block, one node per 16-lane group.
__global__ __launch_bounds__(256, 8) void k_seg1f(
    const int* __restrict__ rp, const uchar* __restrict__ rcnt,
    const int* __restrict__ col,
    const float* __restrict__ as1, const float* __restrict__ ad1,
    const ushort* __restrict__ h1, const float* __restrict__ b1,
    const ushort* __restrict__ wExt,
    ushort* __restrict__ h2, float* __restrict__ as2, float* __restrict__ ad2)
{
    __shared__ __align__(16) ushort zS[BN * 72];
    __shared__ float pS[CHE * 4];
    __shared__ int colS[CHE];
    __shared__ uchar ndS[CHE];
    __shared__ int sRp[BN + 1];
    __shared__ float bS[64];
    __shared__ float adS[BN * 4];

    const int tid = threadIdx.x;
    const int n0 = blockIdx.x * BN;

    if (tid < 64) bS[tid] = b1[tid];
    if (tid < BN * 4) adS[tid] = ad1[(size_t)n0 * 4 + tid];
    if (tid < BN) sRp[tid] = rp[n0 + tid];
    if (tid == BN) sRp[BN] = rp[n0 + BN - 1] + (int)rcnt[n0 + BN - 1];
    __syncthreads();

    const int eb0 = sRp[0];
    const int cnt = min(sRp[BN] - eb0, CHE);

    for (int t = tid; t < cnt; t += 256) {
        int ge = eb0 + t;
        colS[t] = col[ge];
        int nd = 0;
        #pragma unroll
        for (int k = 1; k < BN; ++k) nd += (ge >= sRp[k]);
        ndS[t] = (uchar)nd;
    }
    __syncthreads();
    for (int t = tid; t < cnt * 4; t += 256) {
        int e = t >> 2, hh = t & 3;
        float v = as1[(size_t)colS[e] * 4 + hh] + adS[ndS[e] * 4 + hh];
        pS[t] = __expf(lrelu(v));
    }
    __syncthreads();

    const int w = tid >> 6, lane = tid & 63;
    const int g = lane >> 4, c4 = lane & 15, head = c4 >> 2;
    const int nb = w * 4 + g;
    const int s_n = sRp[nb] - eb0, e_n = sRp[nb + 1] - eb0;

    f32x4 acc = {0, 0, 0, 0};
    float den = 0.f;
    int i = s_n;
    for (; i + 3 < e_n; i += 4) {
        int cA = colS[i], cB = colS[i + 1], cC = colS[i + 2], cD = colS[i + 3];
        ushort4 hA = *(const ushort4*)&h1[(size_t)cA * 64 + c4 * 4];
        ushort4 hB = *(const ushort4*)&h1[(size_t)cB * 64 + c4 * 4];
        ushort4 hC = *(const ushort4*)&h1[(size_t)cC * 64 + c4 * 4];
        ushort4 hD = *(const ushort4*)&h1[(size_t)cD * 64 + c4 * 4];
        float pA = pS[(i + 0) * 4 + head], pB = pS[(i + 1) * 4 + head];
        float pC = pS[(i + 2) * 4 + head], pD = pS[(i + 3) * 4 + head];
        den += (pA + pB) + (pC + pD);
        acc[0] = fmaf(pA, bf2f(hA.x), acc[0]);
        acc[1] = fmaf(pA, bf2f(hA.y), acc[1]);
        acc[2] = fmaf(pA, bf2f(hA.z), acc[2]);
        acc[3] = fmaf(pA, bf2f(hA.w), acc[3]);
        acc[0] = fmaf(pB, bf2f(hB.x), acc[0]);
        acc[1] = fmaf(pB, bf2f(hB.y), acc[1]);
        acc[2] = fmaf(pB, bf2f(hB.z), acc[2]);
        acc[3] = fmaf(pB, bf2f(hB.w), acc[3]);
        acc[0] = fmaf(pC, bf2f(hC.x), acc[0]);
        acc[1] = fmaf(pC, bf2f(hC.y), acc[1]);
        acc[2] = fmaf(pC, bf2f(hC.z), acc[2]);
        acc[3] = fmaf(pC, bf2f(hC.w), acc[3]);
        acc[0] = fmaf(pD, bf2f(hD.x), acc[0]);
        acc[1] = fmaf(pD, bf2f(hD.y), acc[1]);
        acc[2] = fmaf(pD, bf2f(hD.z), acc[2]);
        acc[3] = fmaf(pD, bf2f(hD.w), acc[3]);
    }
    for (; i < e_n; ++i) {
        int cA = colS[i];
        ushort4 hA = *(const ushort4*)&h1[(size_t)cA * 64 + c4 * 4];
        float pA = pS[i * 4 + head];
        den += pA;
        acc[0] = fmaf(pA, bf2f(hA.x), acc[0]);
        acc[1] = fmaf(pA, bf2f(hA.y), acc[1]);
        acc[2] = fmaf(pA, bf2f(hA.z), acc[2]);
        acc[3] = fmaf(pA, bf2f(hA.w), acc[3]);
    }
    {
        float inv = 1.f / (den + 1e-16f);
        ushort4 zv;
        zv.x = f2bf(relu_np(acc[0] * inv + bS[c4 * 4 + 0]));
        zv.y = f2bf(relu_np(acc[1] * inv + bS[c4 * 4 + 1]));
        zv.z = f2bf(relu_np(acc[2] * inv + bS[c4 * 4 + 2]));
        zv.w = f2bf(relu_np(acc[3] * inv + bS[c4 * 4 + 3]));
        *(ushort4*)&zS[nb * 72 + c4 * 4] = zv;
    }
    __syncthreads();

    const int m = c4, quad = g;
    for (int t = w; t < 5; t += 4) {
        f32x4 acct = {0, 0, 0, 0};
        #pragma unroll
        for (int ks = 0; ks < 64; ks += 32) {
            short8 a = *(const short8*)&zS[m * 72 + ks + quad * 8];
            short8 b = *(const short8*)&wExt[(t * 16 + m) * 64 + ks + quad * 8];
            acct = __builtin_amdgcn_mfma_f32_16x16x32_bf16(a, b, acct, 0, 0, 0);
        }
        if (t < 4) {
            #pragma unroll
            for (int r = 0; r < 4; ++r)
                h2[(size_t)(n0 + quad * 4 + r) * 64 + t * 16 + m] = f2bf(acct[r]);
        } else {
            #pragma unroll
            for (int r = 0; r < 4; ++r) {
                int row = n0 + quad * 4 + r;
                if (m == 0) as2[row] = acct[r];
                else if (m == 1) ad2[row] = acct[r];
            }
        }
    }
}

// ---------------- layer-2 seg aggregation + fused classifier head -----------
__global__ __launch_bounds__(256, 8) void k_seg2f(
    const int* __restrict__ rp, const uchar* __restrict__ rcnt,
    const int* __restrict__ col,
    const float* __restrict__ as2, const float* __restrict__ ad2,
    const ushort* __restrict__ h2, const float* __restrict__ b2,
    const float* __restrict__ Wc, const float* __restrict__ bc,
    float* __restrict__ out)
{
    __shared__ float pS[CHE];
    __shared__ int colS[CHE];
    __shared__ uchar ndS[CHE];
    __shared__ int sRp[BN + 1];
    __shared__ float adS[BN];
    __shared__ float b2S[64];
    __shared__ float wcS[64];

    const int tid = threadIdx.x;
    const int n0 = blockIdx.x * BN;
    if (tid < 64) { b2S[tid] = b2[tid]; wcS[tid] = Wc[tid]; }
    if (tid < BN) { sRp[tid] = rp[n0 + tid]; adS[tid] = ad2[n0 + tid]; }
    if (tid == BN) sRp[BN] = rp[n0 + BN - 1] + (int)rcnt[n0 + BN - 1];
    __syncthreads();

    const int eb0 = sRp[0];
    const int cnt = min(sRp[BN] - eb0, CHE);
    for (int t = tid; t < cnt; t += 256) {
        int ge = eb0 + t;
        colS[t] = col[ge];
        int nd = 0;
        #pragma unroll
        for (int k = 1; k < BN; ++k) nd += (ge >= sRp[k]);
        ndS[t] = (uchar)nd;
    }
    __syncthreads();
    for (int t = tid; t < cnt; t += 256)
        pS[t] = __expf(lrelu(as2[colS[t]] + adS[ndS[t]]));
    __syncthreads();

    const int w = tid >> 6, lane = tid & 63;
    const int g = lane >> 4, c4 = lane & 15;
    const int nb = w * 4 + g;
    const int myn = n0 + nb;
    const int s_n = sRp[nb] - eb0, e_n = sRp[nb + 1] - eb0;

    f32x4 acc = {0, 0, 0, 0};
    float den = 0.f;
    int i = s_n;
    for (; i + 3 < e_n; i += 4) {
        int cA = colS[i], cB = colS[i + 1], cC = colS[i + 2], cD = colS[i + 3];
        ushort4 hA = *(const ushort4*)&h2[(size_t)cA * 64 + c4 * 4];
        ushort4 hB = *(const ushort4*)&h2[(size_t)cB * 64 + c4 * 4];
        ushort4 hC = *(const ushort4*)&h2[(size_t)cC * 64 + c4 * 4];
        ushort4 hD = *(const ushort4*)&h2[(size_t)cD * 64 + c4 * 4];
        float pA = pS[i + 0], pB = pS[i + 1], pC = pS[i + 2], pD = pS[i + 3];
        den += (pA + pB) + (pC + pD);
        acc[0] = fmaf(pA, bf2f(hA.x), acc[0]);
        acc[1] = fmaf(pA, bf2f(hA.y), acc[1]);
        acc[2] = fmaf(pA, bf2f(hA.z), acc[2]);
        acc[3] = fmaf(pA, bf2f(hA.w), acc[3]);
        acc[0] = fmaf(pB, bf2f(hB.x), acc[0]);
        acc[1] = fmaf(pB, bf2f(hB.y), acc[1]);
        acc[2] = fmaf(pB, bf2f(hB.z), acc[2]);
        acc[3] = fmaf(pB, bf2f(hB.w), acc[3]);
        acc[0] = fmaf(pC, bf2f(hC.x), acc[0]);
        acc[1] = fmaf(pC, bf2f(hC.y), acc[1]);
        acc[2] = fmaf(pC, bf2f(hC.z), acc[2]);
        acc[3] = fmaf(pC, bf2f(hC.w), acc[3]);
        acc[0] = fmaf(pD, bf2f(hD.x), acc[0]);
        acc[1] = fmaf(pD, bf2f(hD.y), acc[1]);
        acc[2] = fmaf(pD, bf2f(hD.z), acc[2]);
        acc[3] = fmaf(pD, bf2f(hD.w), acc[3]);
    }
    for (; i < e_n; ++i) {
        int cA = colS[i];
        ushort4 hA = *(const ushort4*)&h2[(size_t)cA * 64 + c4 * 4];
        float pA = pS[i];
        den += pA;
        acc[0] = fmaf(pA, bf2f(hA.x), acc[0]);
        acc[1] = fmaf(pA, bf2f(hA.y), acc[1]);
        acc[2] = fmaf(pA, bf2f(hA.z), acc[2]);
        acc[3] = fmaf(pA, bf2f(hA.w), acc[3]);
    }

    float inv = 1.f / (den + 1e-16f);
    float t2 = 0.f;
    #pragma unroll
    for (int j = 0; j < 4; ++j)
        t2 += relu_np(acc[j] * inv + b2S[c4 * 4 + j]) * wcS[c4 * 4 + j];
    t2 += __shfl_xor(t2, 1);
    t2 += __shfl_xor(t2, 2);
    t2 += __shfl_xor(t2, 4);
    t2 += __shfl_xor(t2, 8);
    if (c4 == 0) out[myn] = t2 + bc[0];
}

extern "C" void kernel_launch(void* const* d_in, const int* in_sizes, int n_in,
                              void* d_out, int out_size, void* d_ws, size_t ws_size,
                              hipStream_t stream)
{
    const float* x   = (const float*)d_in[0];
    const int*   ei  = (const int*)d_in[1];
    const float* W1  = (const float*)d_in[2];
    const float* aS1 = (const float*)d_in[3];
    const float* aD1 = (const float*)d_in[4];
    const float* b1  = (const float*)d_in[5];
    const float* W2  = (const float*)d_in[6];
    const float* aS2 = (const float*)d_in[7];
    const float* aD2 = (const float*)d_in[8];
    const float* b2  = (const float*)d_in[9];
    const float* Wc  = (const float*)d_in[10];
    const float* bc  = (const float*)d_in[11];
    float* out = (float*)d_out;

    const int* src = ei;
    const int* dst = ei + EE;

    // ---- workspace layout (~36 MB) ----
    ushort* h1   = (ushort*)d_ws;                     // [N*64] bf16  12.8MB
    ushort* h2   = h1 + (size_t)NN * 64;              // [N*64] bf16  12.8MB
    float*  as1  = (float*)(h2 + (size_t)NN * 64);    // [4N]
    float*  ad1  = as1 + (size_t)NN * 4;              // [4N]
    float*  as2  = ad1 + (size_t)NN * 4;              // [N]
    float*  ad2  = as2 + (size_t)NN;                  // [N]
    ushort* wExt = (ushort*)(ad2 + (size_t)NN);       // [80*64] bf16 10KB
    int* row_ptr = (int*)(wExt + 80 * 64);            // [N]
    uchar* rcnt  = (uchar*)(row_ptr + NN);            // [N] bytes
    int* gcur    = (int*)(rcnt + ((NN + 3) & ~3));    // [NBK] relative counts
    int* done    = gcur + NBK;                        // [1] part-done counter
    int* col     = done + 1;                          // [NBK*CAP] 8MB arena
    int* pairs   = (int*)h2;                          // aliases h2 (dead by seg1)

    // ---- stage 0: zero bucket counters + done flag (788 B) ----
    hipMemsetAsync(gcur, 0, (NBK + 1) * sizeof(int), stream);

    // ---- stage 1: part || gemm1 || wExt, then bucket (flag-ordered) ----
    k_pgb<<<PGB_GRID, 256, 0, stream>>>(src, dst, gcur, done, pairs,
                                        x, W1, aS1, aD1, h1, as1, ad1,
                                        W2, aS2, aD2, wExt,
                                        row_ptr, rcnt, col);

    // ---- stage 2: layer 1 aggregation + fused layer 2 GEMM ----
    k_seg1f<<<NGRP, 256, 0, stream>>>(row_ptr, rcnt, col, as1, ad1, h1, b1,
                                      wExt, h2, as2, ad2);

    // ---- stage 3: layer 2 aggregation + fused classifier ----
    k_seg2f<<<NGRP, 256, 0, stream>>>(row_ptr, rcnt, col, as2, ad2, h2,
                                      b2, Wc, bc, out);
}

// Round 9
// 255.358 us; speedup vs baseline: 1.2278x; 1.2278x over previous
//
#include <hip/hip_runtime.h>
#include <hip/hip_bf16.h>

// ============================================================================
// GAT 2-layer forward, round 23.
// r22 post-mortem: flag-ordered intra-kernel producer->consumer REGRESSED
// (313us, k_pgb 150-164us, VALUBusy 3%): agent-scope fences on non-coherent
// 8-XCD L2s stall everything. Twice-confirmed rule: dispatch boundaries are
// the ONLY cheap device barrier here. Reverted to r19 (252.6us best).
// Counters mined from r21/r22: 9.2M LDS-conflict cycles in part/bucket
// histogram atomics; r19 k_pg/k_bg ~45-48us each, dominated by 782 gemm
// blocks re-staging 40KB W1 into LDS (~5-10us serial latency each).
// Changes vs r19: (1) k_prep (replaces memset): zero gcur + build global bf16
// wB16/wE16/wExt once; gemm reads B-fragments from L2-hot global (seg1f-
// epilogue-proven pattern) -> no LDS staging, no syncthreads, 391 blocks.
// (2) wave-private histograms in part (4x196) and bucket (4x512, reused as
// per-wave scatter cursors) -> ~4x fewer same-address LDS atomic stalls.
// (3) k_pg = part||gemm (782 blocks); k_bg = bucket only (196).
// Facts: fp32 in/out, int32 edge_index, N=100000 E=1600000, bf16 h.
// ============================================================================

typedef __hip_bfloat16 bf16;
typedef unsigned short ushort;
typedef unsigned char uchar;
typedef __attribute__((ext_vector_type(8))) short short8;
typedef __attribute__((ext_vector_type(4))) float f32x4;

#define NN 100000
#define EE 1600000
#define BKB 9
#define BKN (1 << BKB)
#define NBK ((NN + BKN - 1) >> BKB)   // 196
#define CAP 10240                     // arena slots per bucket (max ~8.5K)
#define TILE 4096
#define EPT 16
#define NT ((EE + TILE - 1) / TILE)   // 391 part blocks
#define GP 391                        // gemm blocks (grid-stride, full gemm)
#define BN 16                         // nodes per seg group
#define CHE 512                       // max edges/group: mean 256, +16 sigma
#define NGRP (NN / BN)                // 6250 seg groups

__device__ __forceinline__ float relu_np(float v) { return (v < 0.f) ? 0.f : v; }
__device__ __forceinline__ float lrelu(float v) { return v > 0.f ? v : 0.2f * v; }
__device__ __forceinline__ ushort f2bf(float f) {
    __hip_bfloat16 h = __float2bfloat16(f);
    return *reinterpret_cast<ushort*>(&h);
}
__device__ __forceinline__ float bf2f(ushort u) {
    unsigned int x = ((unsigned int)u) << 16;
    return __uint_as_float(x);
}

// ---- prep: zero gcur + build bf16 weight tables (1 block) ------------------
// wB16[n*128+k] = bf16(W1[k][n]); wE16[j*128+k] = alpha-fold cols (j<8);
// wExt[80*64]: layer-2 W2^T ext (cols 64/65 = W2@aS2 / W2@aD2).
__global__ __launch_bounds__(256) void k_prep(
    int* __restrict__ gcur, const float* __restrict__ W1,
    const float* __restrict__ aS1, const float* __restrict__ aD1,
    const float* __restrict__ W2, const float* __restrict__ aS2,
    const float* __restrict__ aD2,
    ushort* __restrict__ wB16, ushort* __restrict__ wE16,
    ushort* __restrict__ wExt)
{
    const int tid = threadIdx.x;
    if (tid < NBK) gcur[tid] = 0;
    for (int i = tid; i < 128 * 64; i += 256) {
        int k = i >> 6, n = i & 63;
        wB16[n * 128 + k] = f2bf(W1[i]);
    }
    for (int i = tid; i < 128 * 16; i += 256) {
        int k = i >> 4, j = i & 15;
        float v = 0.f;
        if (j < 8) {
            int h = j & 3;
            const float* av = (j < 4) ? aS1 : aD1;
            for (int c = 0; c < 16; ++c)
                v = fmaf(W1[k * 64 + h * 16 + c], av[h * 16 + c], v);
        }
        wE16[j * 128 + k] = f2bf(v);
    }
    for (int i = tid; i < 80 * 64; i += 256) {
        int n = i >> 6, k = i & 63;
        float v = 0.f;
        if (n < 64) {
            v = W2[k * 64 + n];
        } else if (n == 64) {
            for (int c = 0; c < 64; ++c) v = fmaf(W2[k * 64 + c], aS2[c], v);
        } else if (n == 65) {
            for (int c = 0; c < 64; ++c) v = fmaf(W2[k * 64 + c], aD2[c], v);
        }
        wExt[i] = f2bf(v);
    }
}

// ---- fused: part (wave-private hist) || gemm1 (global-B, no LDS) -----------
__global__ __launch_bounds__(256) void k_pg(
    const int* __restrict__ src, const int* __restrict__ dst,
    int* __restrict__ gcur, int* __restrict__ pairs,
    const float* __restrict__ x,
    const ushort* __restrict__ wB16, const ushort* __restrict__ wE16,
    ushort* __restrict__ h1, float* __restrict__ as1, float* __restrict__ ad1)
{
    __shared__ int lh[4][NBK];
    const int bid = blockIdx.x;
    const int tid = threadIdx.x;

    if (bid < NT) {
        // ---- bucketed arena partition, wave-private histograms ----
        for (int i = tid; i < 4 * NBK; i += 256) ((int*)lh)[i] = 0;
        __syncthreads();
        const int wv = tid >> 6;
        const int e0 = bid * TILE;
        int pk[EPT], bk[EPT], rv[EPT];
        #pragma unroll
        for (int j = 0; j < EPT; ++j) {
            int e = e0 + j * 256 + tid;
            if (e < EE) {
                int d = dst[e];
                bk[j] = d >> BKB;
                pk[j] = src[e] | ((d & (BKN - 1)) << 17);
                rv[j] = atomicAdd(&lh[wv][bk[j]], 1);
            }
        }
        __syncthreads();
        for (int i = tid; i < NBK; i += 256) {
            int c0 = lh[0][i], c1 = lh[1][i], c2 = lh[2][i], c3 = lh[3][i];
            int tot = c0 + c1 + c2 + c3;
            int b = tot ? atomicAdd(&gcur[i], tot) : 0;
            lh[0][i] = b;
            lh[1][i] = b + c0;
            lh[2][i] = b + c0 + c1;
            lh[3][i] = b + c0 + c1 + c2;
        }
        __syncthreads();
        #pragma unroll
        for (int j = 0; j < EPT; ++j) {
            int e = e0 + j * 256 + tid;
            if (e < EE)
                pairs[(size_t)bk[j] * CAP + lh[wv][bk[j]] + rv[j]] = pk[j];
        }
    } else {
        // ---- gemm1: B fragments from global bf16 tables (L2-hot 20KB) ----
        const int gb = bid - NT;
        const int w = tid >> 6, lane = tid & 63;
        const int m = lane & 15, quad = lane >> 4;
        const int ntiles = NN >> 4;
        for (int tile = gb * 4 + w; tile < ntiles; tile += GP * 4) {
            const int row0 = tile << 4;
            f32x4 acc[4] = {f32x4{0,0,0,0}, f32x4{0,0,0,0},
                            f32x4{0,0,0,0}, f32x4{0,0,0,0}};
            f32x4 acc5 = {0, 0, 0, 0};
            const float* xp = x + (size_t)(row0 + m) * 128 + quad * 8;
            #pragma unroll
            for (int ks = 0; ks < 128; ks += 32) {
                f32x4 x0 = *(const f32x4*)(xp + ks);
                f32x4 x1 = *(const f32x4*)(xp + ks + 4);
                short8 a;
                #pragma unroll
                for (int j = 0; j < 4; ++j) a[j] = (short)f2bf(x0[j]);
                #pragma unroll
                for (int j = 0; j < 4; ++j) a[4 + j] = (short)f2bf(x1[j]);
                #pragma unroll
                for (int t = 0; t < 4; ++t) {
                    short8 b = *(const short8*)&wB16[(t * 16 + m) * 128 + ks + quad * 8];
                    acc[t] = __builtin_amdgcn_mfma_f32_16x16x32_bf16(a, b, acc[t], 0, 0, 0);
                }
                short8 b5 = *(const short8*)&wE16[m * 128 + ks + quad * 8];
                acc5 = __builtin_amdgcn_mfma_f32_16x16x32_bf16(a, b5, acc5, 0, 0, 0);
            }
            #pragma unroll
            for (int t = 0; t < 4; ++t)
                #pragma unroll
                for (int r = 0; r < 4; ++r)
                    h1[(size_t)(row0 + quad * 4 + r) * 64 + t * 16 + m] = f2bf(acc[t][r]);
            #pragma unroll
            for (int r = 0; r < 4; ++r) {
                int row = row0 + quad * 4 + r;
                if (m < 4) as1[row * 4 + m] = acc5[r];
                else if (m < 8) ad1[row * 4 + (m - 4)] = acc5[r];
            }
        }
    }
}

// ---- bucket: node hist (wave-private) + scan -> CSR ------------------------
__global__ __launch_bounds__(256) void k_bg(
    const int* __restrict__ gcur, const int* __restrict__ pairs,
    int* __restrict__ row_ptr, uchar* __restrict__ rcnt,
    int* __restrict__ col)
{
    __shared__ int h4[4][BKN];    // counts, then per-wave scatter cursors
    __shared__ int sP[256];
    const int b = blockIdx.x;
    const int n0 = b << BKB;
    const int tid = threadIdx.x;
    const int wv = tid >> 6;
    const int base = b * CAP, endE = base + gcur[b];

    for (int i = tid; i < 4 * BKN; i += 256) ((int*)h4)[i] = 0;
    __syncthreads();
    for (int i = base + tid; i < endE; i += 256)
        atomicAdd(&h4[wv][pairs[i] >> 17], 1);
    __syncthreads();

    const int na = 2 * tid, nb2 = 2 * tid + 1;
    int c00 = h4[0][na], c01 = h4[1][na], c02 = h4[2][na], c03 = h4[3][na];
    int c10 = h4[0][nb2], c11 = h4[1][nb2], c12 = h4[2][nb2], c13 = h4[3][nb2];
    int a0 = c00 + c01 + c02 + c03;
    int a1 = c10 + c11 + c12 + c13;
    int tot = a0 + a1;
    sP[tid] = tot;
    __syncthreads();
    for (int off = 1; off < 256; off <<= 1) {
        int t = (tid >= off) ? sP[tid - off] : 0;
        __syncthreads();
        sP[tid] += t;
        __syncthreads();
    }
    const int excl = sP[tid] - tot;
    const int c0 = base + excl;
    const int c1 = c0 + a0;
    if (n0 + na < NN) {
        row_ptr[n0 + na] = c0;
        rcnt[n0 + na] = (uchar)a0;
    }
    if (n0 + nb2 < NN) {
        row_ptr[n0 + nb2] = c1;
        rcnt[n0 + nb2] = (uchar)a1;
    }
    h4[0][na] = c0;
    h4[1][na] = c0 + c00;
    h4[2][na] = c0 + c00 + c01;
    h4[3][na] = c0 + c00 + c01 + c02;
    h4[0][nb2] = c1;
    h4[1][nb2] = c1 + c10;
    h4[2][nb2] = c1 + c10 + c11;
    h4[3][nb2] = c1 + c10 + c11 + c12;
    __syncthreads();
    for (int i = base + tid; i < endE; i += 256) {
        int pr = pairs[i];
        int p = atomicAdd(&h4[wv][pr >> 17], 1);
        col[p] = pr & 0x1FFFF;
    }
}

// ---------------- layer-1 seg aggregation + fused layer-2 GEMM ---------------
// (byte-identical to r19) 16 nodes/block, one node per 16-lane group.
__global__ __launch_bounds__(256, 8) void k_seg1f(
    const int* __restrict__ rp, const uchar* __restrict__ rcnt,
    const int* __restrict__ col,
    const float* __restrict__ as1, const float* __restrict__ ad1,
    const ushort* __restrict__ h1, const float* __restrict__ b1,
    const ushort* __restrict__ wExt,
    ushort* __restrict__ h2, float* __restrict__ as2, float* __restrict__ ad2)
{
    __shared__ __align__(16) ushort zS[BN * 72];
    __shared__ float pS[CHE * 4];
    __shared__ int colS[CHE];
    __shared__ uchar ndS[CHE];
    __shared__ int sRp[BN + 1];
    __shared__ float bS[64];
    __shared__ float adS[BN * 4];

    const int tid = threadIdx.x;
    const int n0 = blockIdx.x * BN;

    if (tid < 64) bS[tid] = b1[tid];
    if (tid < BN * 4) adS[tid] = ad1[(size_t)n0 * 4 + tid];
    if (tid < BN) sRp[tid] = rp[n0 + tid];
    if (tid == BN) sRp[BN] = rp[n0 + BN - 1] + (int)rcnt[n0 + BN - 1];
    __syncthreads();

    const int eb0 = sRp[0];
    const int cnt = min(sRp[BN] - eb0, CHE);

    for (int t = tid; t < cnt; t += 256) {
        int ge = eb0 + t;
        colS[t] = col[ge];
        int nd = 0;
        #pragma unroll
        for (int k = 1; k < BN; ++k) nd += (ge >= sRp[k]);
        ndS[t] = (uchar)nd;
    }
    __syncthreads();
    for (int t = tid; t < cnt * 4; t += 256) {
        int e = t >> 2, hh = t & 3;
        float v = as1[(size_t)colS[e] * 4 + hh] + adS[ndS[e] * 4 + hh];
        pS[t] = __expf(lrelu(v));
    }
    __syncthreads();

    const int w = tid >> 6, lane = tid & 63;
    const int g = lane >> 4, c4 = lane & 15, head = c4 >> 2;
    const int nb = w * 4 + g;
    const int s_n = sRp[nb] - eb0, e_n = sRp[nb + 1] - eb0;

    f32x4 acc = {0, 0, 0, 0};
    float den = 0.f;
    int i = s_n;
    for (; i + 3 < e_n; i += 4) {
        int cA = colS[i], cB = colS[i + 1], cC = colS[i + 2], cD = colS[i + 3];
        ushort4 hA = *(const ushort4*)&h1[(size_t)cA * 64 + c4 * 4];
        ushort4 hB = *(const ushort4*)&h1[(size_t)cB * 64 + c4 * 4];
        ushort4 hC = *(const ushort4*)&h1[(size_t)cC * 64 + c4 * 4];
        ushort4 hD = *(const ushort4*)&h1[(size_t)cD * 64 + c4 * 4];
        float pA = pS[(i + 0) * 4 + head], pB = pS[(i + 1) * 4 + head];
        float pC = pS[(i + 2) * 4 + head], pD = pS[(i + 3) * 4 + head];
        den += (pA + pB) + (pC + pD);
        acc[0] = fmaf(pA, bf2f(hA.x), acc[0]);
        acc[1] = fmaf(pA, bf2f(hA.y), acc[1]);
        acc[2] = fmaf(pA, bf2f(hA.z), acc[2]);
        acc[3] = fmaf(pA, bf2f(hA.w), acc[3]);
        acc[0] = fmaf(pB, bf2f(hB.x), acc[0]);
        acc[1] = fmaf(pB, bf2f(hB.y), acc[1]);
        acc[2] = fmaf(pB, bf2f(hB.z), acc[2]);
        acc[3] = fmaf(pB, bf2f(hB.w), acc[3]);
        acc[0] = fmaf(pC, bf2f(hC.x), acc[0]);
        acc[1] = fmaf(pC, bf2f(hC.y), acc[1]);
        acc[2] = fmaf(pC, bf2f(hC.z), acc[2]);
        acc[3] = fmaf(pC, bf2f(hC.w), acc[3]);
        acc[0] = fmaf(pD, bf2f(hD.x), acc[0]);
        acc[1] = fmaf(pD, bf2f(hD.y), acc[1]);
        acc[2] = fmaf(pD, bf2f(hD.z), acc[2]);
        acc[3] = fmaf(pD, bf2f(hD.w), acc[3]);
    }
    for (; i < e_n; ++i) {
        int cA = colS[i];
        ushort4 hA = *(const ushort4*)&h1[(size_t)cA * 64 + c4 * 4];
        float pA = pS[i * 4 + head];
        den += pA;
        acc[0] = fmaf(pA, bf2f(hA.x), acc[0]);
        acc[1] = fmaf(pA, bf2f(hA.y), acc[1]);
        acc[2] = fmaf(pA, bf2f(hA.z), acc[2]);
        acc[3] = fmaf(pA, bf2f(hA.w), acc[3]);
    }
    {
        float inv = 1.f / (den + 1e-16f);
        ushort4 zv;
        zv.x = f2bf(relu_np(acc[0] * inv + bS[c4 * 4 + 0]));
        zv.y = f2bf(relu_np(acc[1] * inv + bS[c4 * 4 + 1]));
        zv.z = f2bf(relu_np(acc[2] * inv + bS[c4 * 4 + 2]));
        zv.w = f2bf(relu_np(acc[3] * inv + bS[c4 * 4 + 3]));
        *(ushort4*)&zS[nb * 72 + c4 * 4] = zv;
    }
    __syncthreads();

    const int m = c4, quad = g;
    for (int t = w; t < 5; t += 4) {
        f32x4 acct = {0, 0, 0, 0};
        #pragma unroll
        for (int ks = 0; ks < 64; ks += 32) {
            short8 a = *(const short8*)&zS[m * 72 + ks + quad * 8];
            short8 b = *(const short8*)&wExt[(t * 16 + m) * 64 + ks + quad * 8];
            acct = __builtin_amdgcn_mfma_f32_16x16x32_bf16(a, b, acct, 0, 0, 0);
        }
        if (t < 4) {
            #pragma unroll
            for (int r = 0; r < 4; ++r)
                h2[(size_t)(n0 + quad * 4 + r) * 64 + t * 16 + m] = f2bf(acct[r]);
        } else {
            #pragma unroll
            for (int r = 0; r < 4; ++r) {
                int row = n0 + quad * 4 + r;
                if (m == 0) as2[row] = acct[r];
                else if (m == 1) ad2[row] = acct[r];
            }
        }
    }
}

// ---------------- layer-2 seg aggregation + fused classifier head -----------
__global__ __launch_bounds__(256, 8) void k_seg2f(
    const int* __restrict__ rp, const uchar* __restrict__ rcnt,
    const int* __restrict__ col,
    const float* __restrict__ as2, const float* __restrict__ ad2,
    const ushort* __restrict__ h2, const float* __restrict__ b2,
    const float* __restrict__ Wc, const float* __restrict__ bc,
    float* __restrict__ out)
{
    __shared__ float pS[CHE];
    __shared__ int colS[CHE];
    __shared__ uchar ndS[CHE];
    __shared__ int sRp[BN + 1];
    __shared__ float adS[BN];
    __shared__ float b2S[64];
    __shared__ float wcS[64];

    const int tid = threadIdx.x;
    const int n0 = blockIdx.x * BN;
    if (tid < 64) { b2S[tid] = b2[tid]; wcS[tid] = Wc[tid]; }
    if (tid < BN) { sRp[tid] = rp[n0 + tid]; adS[tid] = ad2[n0 + tid]; }
    if (tid == BN) sRp[BN] = rp[n0 + BN - 1] + (int)rcnt[n0 + BN - 1];
    __syncthreads();

    const int eb0 = sRp[0];
    const int cnt = min(sRp[BN] - eb0, CHE);
    for (int t = tid; t < cnt; t += 256) {
        int ge = eb0 + t;
        colS[t] = col[ge];
        int nd = 0;
        #pragma unroll
        for (int k = 1; k < BN; ++k) nd += (ge >= sRp[k]);
        ndS[t] = (uchar)nd;
    }
    __syncthreads();
    for (int t = tid; t < cnt; t += 256)
        pS[t] = __expf(lrelu(as2[colS[t]] + adS[ndS[t]]));
    __syncthreads();

    const int w = tid >> 6, lane = tid & 63;
    const int g = lane >> 4, c4 = lane & 15;
    const int nb = w * 4 + g;
    const int myn = n0 + nb;
    const int s_n = sRp[nb] - eb0, e_n = sRp[nb + 1] - eb0;

    f32x4 acc = {0, 0, 0, 0};
    float den = 0.f;
    int i = s_n;
    for (; i + 3 < e_n; i += 4) {
        int cA = colS[i], cB = colS[i + 1], cC = colS[i + 2], cD = colS[i + 3];
        ushort4 hA = *(const ushort4*)&h2[(size_t)cA * 64 + c4 * 4];
        ushort4 hB = *(const ushort4*)&h2[(size_t)cB * 64 + c4 * 4];
        ushort4 hC = *(const ushort4*)&h2[(size_t)cC * 64 + c4 * 4];
        ushort4 hD = *(const ushort4*)&h2[(size_t)cD * 64 + c4 * 4];
        float pA = pS[i + 0], pB = pS[i + 1], pC = pS[i + 2], pD = pS[i + 3];
        den += (pA + pB) + (pC + pD);
        acc[0] = fmaf(pA, bf2f(hA.x), acc[0]);
        acc[1] = fmaf(pA, bf2f(hA.y), acc[1]);
        acc[2] = fmaf(pA, bf2f(hA.z), acc[2]);
        acc[3] = fmaf(pA, bf2f(hA.w), acc[3]);
        acc[0] = fmaf(pB, bf2f(hB.x), acc[0]);
        acc[1] = fmaf(pB, bf2f(hB.y), acc[1]);
        acc[2] = fmaf(pB, bf2f(hB.z), acc[2]);
        acc[3] = fmaf(pB, bf2f(hB.w), acc[3]);
        acc[0] = fmaf(pC, bf2f(hC.x), acc[0]);
        acc[1] = fmaf(pC, bf2f(hC.y), acc[1]);
        acc[2] = fmaf(pC, bf2f(hC.z), acc[2]);
        acc[3] = fmaf(pC, bf2f(hC.w), acc[3]);
        acc[0] = fmaf(pD, bf2f(hD.x), acc[0]);
        acc[1] = fmaf(pD, bf2f(hD.y), acc[1]);
        acc[2] = fmaf(pD, bf2f(hD.z), acc[2]);
        acc[3] = fmaf(pD, bf2f(hD.w), acc[3]);
    }
    for (; i < e_n; ++i) {
        int cA = colS[i];
        ushort4 hA = *(const ushort4*)&h2[(size_t)cA * 64 + c4 * 4];
        float pA = pS[i];
        den += pA;
        acc[0] = fmaf(pA, bf2f(hA.x), acc[0]);
        acc[1] = fmaf(pA, bf2f(hA.y), acc[1]);
        acc[2] = fmaf(pA, bf2f(hA.z), acc[2]);
        acc[3] = fmaf(pA, bf2f(hA.w), acc[3]);
    }

    float inv = 1.f / (den + 1e-16f);
    float t2 = 0.f;
    #pragma unroll
    for (int j = 0; j < 4; ++j)
        t2 += relu_np(acc[j] * inv + b2S[c4 * 4 + j]) * wcS[c4 * 4 + j];
    t2 += __shfl_xor(t2, 1);
    t2 += __shfl_xor(t2, 2);
    t2 += __shfl_xor(t2, 4);
    t2 += __shfl_xor(t2, 8);
    if (c4 == 0) out[myn] = t2 + bc[0];
}

extern "C" void kernel_launch(void* const* d_in, const int* in_sizes, int n_in,
                              void* d_out, int out_size, void* d_ws, size_t ws_size,
                              hipStream_t stream)
{
    const float* x   = (const float*)d_in[0];
    const int*   ei  = (const int*)d_in[1];
    const float* W1  = (const float*)d_in[2];
    const float* aS1 = (const float*)d_in[3];
    const float* aD1 = (const float*)d_in[4];
    const float* b1  = (const float*)d_in[5];
    const float* W2  = (const float*)d_in[6];
    const float* aS2 = (const float*)d_in[7];
    const float* aD2 = (const float*)d_in[8];
    const float* b2  = (const float*)d_in[9];
    const float* Wc  = (const float*)d_in[10];
    const float* bc  = (const float*)d_in[11];
    float* out = (float*)d_out;

    const int* src = ei;
    const int* dst = ei + EE;

    // ---- workspace layout (~38 MB) ----
    ushort* h1   = (ushort*)d_ws;                     // [N*64] bf16  12.8MB
    ushort* h2   = h1 + (size_t)NN * 64;              // [N*64] bf16  12.8MB
    float*  as1  = (float*)(h2 + (size_t)NN * 64);    // [4N]
    float*  ad1  = as1 + (size_t)NN * 4;              // [4N]
    float*  as2  = ad1 + (size_t)NN * 4;              // [N]
    float*  ad2  = as2 + (size_t)NN;                  // [N]
    ushort* wExt = (ushort*)(ad2 + (size_t)NN);       // [80*64] bf16 10KB
    ushort* wB16 = wExt + 80 * 64;                    // [64*128] bf16 16KB
    ushort* wE16 = wB16 + 64 * 128;                   // [16*128] bf16 4KB
    int* row_ptr = (int*)(wE16 + 16 * 128);           // [N]
    uchar* rcnt  = (uchar*)(row_ptr + NN);            // [N] bytes
    int* gcur    = (int*)(rcnt + ((NN + 3) & ~3));    // [NBK] relative counts
    int* col     = gcur + NBK;                        // [NBK*CAP] 8MB arena
    int* pairs   = (int*)h2;                          // aliases h2 (dead by seg1)

    // ---- stage 0: zero cursors + build bf16 weight tables ----
    k_prep<<<1, 256, 0, stream>>>(gcur, W1, aS1, aD1, W2, aS2, aD2,
                                  wB16, wE16, wExt);

    // ---- stage 1: part (wave-private hist) || gemm1 (global-B) ----
    k_pg<<<NT + GP, 256, 0, stream>>>(src, dst, gcur, pairs, x,
                                      wB16, wE16, h1, as1, ad1);

    // ---- stage 2: bucket CSR finalize ----
    k_bg<<<NBK, 256, 0, stream>>>(gcur, pairs, row_ptr, rcnt, col);

    // ---- stage 3: layer 1 aggregation + fused layer 2 GEMM ----
    k_seg1f<<<NGRP, 256, 0, stream>>>(row_ptr, rcnt, col, as1, ad1, h1, b1,
                                      wExt, h2, as2, ad2);

    // ---- stage 4: layer 2 aggregation + fused classifier ----
    k_seg2f<<<NGRP, 256, 0, stream>>>(row_ptr, rcnt, col, as2, ad2, h2,
                                      b2, Wc, bc, out);
}

// Round 10
// 240.381 us; speedup vs baseline: 1.3043x; 1.0623x over previous
//
#include <hip/hip_runtime.h>
#include <hip/hip_bf16.h>

// ============================================================================
// GAT 2-layer forward, round 24.
// r23 post-mortem: front-end micro-opts (global-B gemm, wave-private hist)
// were NEUTRAL (255.4 vs 252.6) — seg kernels pinned at the 2.5TB/s fill
// ceiling; the other ~160us pool is mostly per-dispatch overhead (~20us x 5),
// not work. r20/r22: intra-kernel sync is ruined by fence costs on the
// non-coherent 8-XCD L2s -> the only safe merge is dispatch-graph repacking.
// Change (zero numeric change): gemm1 depends only on weight tables, not on
// part -> move it into the bucket dispatch. 4 kernels + 1 tiny memset:
//   memset(gcur,784B) -> k_pt{part(391) || table-build(2)}
//   -> k_bgg{bucket(196) || gemm1(391, global-B)} -> seg1f -> seg2f.
// Pairs LDS/atomic-heavy bucket with BW-heavy gemm (complementary pipes).
// All bodies byte-identical to r23.
// Facts: fp32 in/out, int32 edge_index, N=100000 E=1600000, bf16 h.
// ============================================================================

typedef __hip_bfloat16 bf16;
typedef unsigned short ushort;
typedef unsigned char uchar;
typedef __attribute__((ext_vector_type(8))) short short8;
typedef __attribute__((ext_vector_type(4))) float f32x4;

#define NN 100000
#define EE 1600000
#define BKB 9
#define BKN (1 << BKB)
#define NBK ((NN + BKN - 1) >> BKB)   // 196
#define CAP 10240                     // arena slots per bucket (max ~8.5K)
#define TILE 4096
#define EPT 16
#define NT ((EE + TILE - 1) / TILE)   // 391 part blocks
#define GP 391                        // gemm blocks (grid-stride anchor)
#define BN 16                         // nodes per seg group
#define CHE 512                       // max edges/group: mean 256, +16 sigma
#define NGRP (NN / BN)                // 6250 seg groups

__device__ __forceinline__ float relu_np(float v) { return (v < 0.f) ? 0.f : v; }
__device__ __forceinline__ float lrelu(float v) { return v > 0.f ? v : 0.2f * v; }
__device__ __forceinline__ ushort f2bf(float f) {
    __hip_bfloat16 h = __float2bfloat16(f);
    return *reinterpret_cast<ushort*>(&h);
}
__device__ __forceinline__ float bf2f(ushort u) {
    unsigned int x = ((unsigned int)u) << 16;
    return __uint_as_float(x);
}

// ---- dispatch 1: part (wave-private hist) || weight-table build ------------
__global__ __launch_bounds__(256) void k_pt(
    const int* __restrict__ src, const int* __restrict__ dst,
    int* __restrict__ gcur, int* __restrict__ pairs,
    const float* __restrict__ W1,
    const float* __restrict__ aS1, const float* __restrict__ aD1,
    const float* __restrict__ W2, const float* __restrict__ aS2,
    const float* __restrict__ aD2,
    ushort* __restrict__ wB16, ushort* __restrict__ wE16,
    ushort* __restrict__ wExt)
{
    __shared__ int lh[4][NBK];
    const int bid = blockIdx.x;
    const int tid = threadIdx.x;

    if (bid < NT) {
        // ---- bucketed arena partition, wave-private histograms ----
        for (int i = tid; i < 4 * NBK; i += 256) ((int*)lh)[i] = 0;
        __syncthreads();
        const int wv = tid >> 6;
        const int e0 = bid * TILE;
        int pk[EPT], bk[EPT], rv[EPT];
        #pragma unroll
        for (int j = 0; j < EPT; ++j) {
            int e = e0 + j * 256 + tid;
            if (e < EE) {
                int d = dst[e];
                bk[j] = d >> BKB;
                pk[j] = src[e] | ((d & (BKN - 1)) << 17);
                rv[j] = atomicAdd(&lh[wv][bk[j]], 1);
            }
        }
        __syncthreads();
        for (int i = tid; i < NBK; i += 256) {
            int c0 = lh[0][i], c1 = lh[1][i], c2 = lh[2][i], c3 = lh[3][i];
            int tot = c0 + c1 + c2 + c3;
            int b = tot ? atomicAdd(&gcur[i], tot) : 0;
            lh[0][i] = b;
            lh[1][i] = b + c0;
            lh[2][i] = b + c0 + c1;
            lh[3][i] = b + c0 + c1 + c2;
        }
        __syncthreads();
        #pragma unroll
        for (int j = 0; j < EPT; ++j) {
            int e = e0 + j * 256 + tid;
            if (e < EE)
                pairs[(size_t)bk[j] * CAP + lh[wv][bk[j]] + rv[j]] = pk[j];
        }
    } else if (bid == NT) {
        // ---- wB16[n*128+k]=bf16(W1[k][n]); wE16 alpha-fold cols ----
        for (int i = tid; i < 128 * 64; i += 256) {
            int k = i >> 6, n = i & 63;
            wB16[n * 128 + k] = f2bf(W1[i]);
        }
        for (int i = tid; i < 128 * 16; i += 256) {
            int k = i >> 4, j = i & 15;
            float v = 0.f;
            if (j < 8) {
                int h = j & 3;
                const float* av = (j < 4) ? aS1 : aD1;
                for (int c = 0; c < 16; ++c)
                    v = fmaf(W1[k * 64 + h * 16 + c], av[h * 16 + c], v);
            }
            wE16[j * 128 + k] = f2bf(v);
        }
    } else {
        // ---- wExt^T bf16 [80][64]: n<64: W2 col n; 64: W2@aS2; 65: W2@aD2 --
        for (int i = tid; i < 80 * 64; i += 256) {
            int n = i >> 6, k = i & 63;
            float v = 0.f;
            if (n < 64) {
                v = W2[k * 64 + n];
            } else if (n == 64) {
                for (int c = 0; c < 64; ++c) v = fmaf(W2[k * 64 + c], aS2[c], v);
            } else if (n == 65) {
                for (int c = 0; c < 64; ++c) v = fmaf(W2[k * 64 + c], aD2[c], v);
            }
            wExt[i] = f2bf(v);
        }
    }
}

// ---- dispatch 2: bucket (wave-private) || gemm1 (global-B, no LDS) ---------
__global__ __launch_bounds__(256) void k_bgg(
    const int* __restrict__ gcur, const int* __restrict__ pairs,
    int* __restrict__ row_ptr, uchar* __restrict__ rcnt,
    int* __restrict__ col,
    const float* __restrict__ x,
    const ushort* __restrict__ wB16, const ushort* __restrict__ wE16,
    ushort* __restrict__ h1, float* __restrict__ as1, float* __restrict__ ad1)
{
    __shared__ int h4[4][BKN];    // counts, then per-wave scatter cursors
    __shared__ int sP[256];
    const int bid = blockIdx.x;
    const int tid = threadIdx.x;

    if (bid >= NBK) {
        // ---- gemm1: B fragments from global bf16 tables (L2-hot 20KB) ----
        const int gb = bid - NBK;
        const int w = tid >> 6, lane = tid & 63;
        const int m = lane & 15, quad = lane >> 4;
        const int ntiles = NN >> 4;
        for (int tile = gb * 4 + w; tile < ntiles; tile += GP * 4) {
            const int row0 = tile << 4;
            f32x4 acc[4] = {f32x4{0,0,0,0}, f32x4{0,0,0,0},
                            f32x4{0,0,0,0}, f32x4{0,0,0,0}};
            f32x4 acc5 = {0, 0, 0, 0};
            const float* xp = x + (size_t)(row0 + m) * 128 + quad * 8;
            #pragma unroll
            for (int ks = 0; ks < 128; ks += 32) {
                f32x4 x0 = *(const f32x4*)(xp + ks);
                f32x4 x1 = *(const f32x4*)(xp + ks + 4);
                short8 a;
                #pragma unroll
                for (int j = 0; j < 4; ++j) a[j] = (short)f2bf(x0[j]);
                #pragma unroll
                for (int j = 0; j < 4; ++j) a[4 + j] = (short)f2bf(x1[j]);
                #pragma unroll
                for (int t = 0; t < 4; ++t) {
                    short8 b = *(const short8*)&wB16[(t * 16 + m) * 128 + ks + quad * 8];
                    acc[t] = __builtin_amdgcn_mfma_f32_16x16x32_bf16(a, b, acc[t], 0, 0, 0);
                }
                short8 b5 = *(const short8*)&wE16[m * 128 + ks + quad * 8];
                acc5 = __builtin_amdgcn_mfma_f32_16x16x32_bf16(a, b5, acc5, 0, 0, 0);
            }
            #pragma unroll
            for (int t = 0; t < 4; ++t)
                #pragma unroll
                for (int r = 0; r < 4; ++r)
                    h1[(size_t)(row0 + quad * 4 + r) * 64 + t * 16 + m] = f2bf(acc[t][r]);
            #pragma unroll
            for (int r = 0; r < 4; ++r) {
                int row = row0 + quad * 4 + r;
                if (m < 4) as1[row * 4 + m] = acc5[r];
                else if (m < 8) ad1[row * 4 + (m - 4)] = acc5[r];
            }
        }
        return;
    }

    // ---- bucket: node hist (wave-private) + scan -> CSR ----
    const int b = bid;
    const int n0 = b << BKB;
    const int wv = tid >> 6;
    const int base = b * CAP, endE = base + gcur[b];

    for (int i = tid; i < 4 * BKN; i += 256) ((int*)h4)[i] = 0;
    __syncthreads();
    for (int i = base + tid; i < endE; i += 256)
        atomicAdd(&h4[wv][pairs[i] >> 17], 1);
    __syncthreads();

    const int na = 2 * tid, nb2 = 2 * tid + 1;
    int c00 = h4[0][na], c01 = h4[1][na], c02 = h4[2][na], c03 = h4[3][na];
    int c10 = h4[0][nb2], c11 = h4[1][nb2], c12 = h4[2][nb2], c13 = h4[3][nb2];
    int a0 = c00 + c01 + c02 + c03;
    int a1 = c10 + c11 + c12 + c13;
    int tot = a0 + a1;
    sP[tid] = tot;
    __syncthreads();
    for (int off = 1; off < 256; off <<= 1) {
        int t = (tid >= off) ? sP[tid - off] : 0;
        __syncthreads();
        sP[tid] += t;
        __syncthreads();
    }
    const int excl = sP[tid] - tot;
    const int c0 = base + excl;
    const int c1 = c0 + a0;
    if (n0 + na < NN) {
        row_ptr[n0 + na] = c0;
        rcnt[n0 + na] = (uchar)a0;
    }
    if (n0 + nb2 < NN) {
        row_ptr[n0 + nb2] = c1;
        rcnt[n0 + nb2] = (uchar)a1;
    }
    h4[0][na] = c0;
    h4[1][na] = c0 + c00;
    h4[2][na] = c0 + c00 + c01;
    h4[3][na] = c0 + c00 + c01 + c02;
    h4[0][nb2] = c1;
    h4[1][nb2] = c1 + c10;
    h4[2][nb2] = c1 + c10 + c11;
    h4[3][nb2] = c1 + c10 + c11 + c12;
    __syncthreads();
    for (int i = base + tid; i < endE; i += 256) {
        int pr = pairs[i];
        int p = atomicAdd(&h4[wv][pr >> 17], 1);
        col[p] = pr & 0x1FFFF;
    }
}

// ---------------- layer-1 seg aggregation + fused layer-2 GEMM ---------------
// (byte-identical to r23) 16 nodes/block, one node per 16-lane group.
__global__ __launch_bounds__(256, 8) void k_seg1f(
    const int* __restrict__ rp, const uchar* __restrict__ rcnt,
    const int* __restrict__ col,
    const float* __restrict__ as1, const float* __restrict__ ad1,
    const ushort* __restrict__ h1, const float* __restrict__ b1,
    const ushort* __restrict__ wExt,
    ushort* __restrict__ h2, float* __restrict__ as2, float* __restrict__ ad2)
{
    __shared__ __align__(16) ushort zS[BN * 72];
    __shared__ float pS[CHE * 4];
    __shared__ int colS[CHE];
    __shared__ uchar ndS[CHE];
    __shared__ int sRp[BN + 1];
    __shared__ float bS[64];
    __shared__ float adS[BN * 4];

    const int tid = threadIdx.x;
    const int n0 = blockIdx.x * BN;

    if (tid < 64) bS[tid] = b1[tid];
    if (tid < BN * 4) adS[tid] = ad1[(size_t)n0 * 4 + tid];
    if (tid < BN) sRp[tid] = rp[n0 + tid];
    if (tid == BN) sRp[BN] = rp[n0 + BN - 1] + (int)rcnt[n0 + BN - 1];
    __syncthreads();

    const int eb0 = sRp[0];
    const int cnt = min(sRp[BN] - eb0, CHE);

    for (int t = tid; t < cnt; t += 256) {
        int ge = eb0 + t;
        colS[t] = col[ge];
        int nd = 0;
        #pragma unroll
        for (int k = 1; k < BN; ++k) nd += (ge >= sRp[k]);
        ndS[t] = (uchar)nd;
    }
    __syncthreads();
    for (int t = tid; t < cnt * 4; t += 256) {
        int e = t >> 2, hh = t & 3;
        float v = as1[(size_t)colS[e] * 4 + hh] + adS[ndS[e] * 4 + hh];
        pS[t] = __expf(lrelu(v));
    }
    __syncthreads();

    const int w = tid >> 6, lane = tid & 63;
    const int g = lane >> 4, c4 = lane & 15, head = c4 >> 2;
    const int nb = w * 4 + g;
    const int s_n = sRp[nb] - eb0, e_n = sRp[nb + 1] - eb0;

    f32x4 acc = {0, 0, 0, 0};
    float den = 0.f;
    int i = s_n;
    for (; i + 3 < e_n; i += 4) {
        int cA = colS[i], cB = colS[i + 1], cC = colS[i + 2], cD = colS[i + 3];
        ushort4 hA = *(const ushort4*)&h1[(size_t)cA * 64 + c4 * 4];
        ushort4 hB = *(const ushort4*)&h1[(size_t)cB * 64 + c4 * 4];
        ushort4 hC = *(const ushort4*)&h1[(size_t)cC * 64 + c4 * 4];
        ushort4 hD = *(const ushort4*)&h1[(size_t)cD * 64 + c4 * 4];
        float pA = pS[(i + 0) * 4 + head], pB = pS[(i + 1) * 4 + head];
        float pC = pS[(i + 2) * 4 + head], pD = pS[(i + 3) * 4 + head];
        den += (pA + pB) + (pC + pD);
        acc[0] = fmaf(pA, bf2f(hA.x), acc[0]);
        acc[1] = fmaf(pA, bf2f(hA.y), acc[1]);
        acc[2] = fmaf(pA, bf2f(hA.z), acc[2]);
        acc[3] = fmaf(pA, bf2f(hA.w), acc[3]);
        acc[0] = fmaf(pB, bf2f(hB.x), acc[0]);
        acc[1] = fmaf(pB, bf2f(hB.y), acc[1]);
        acc[2] = fmaf(pB, bf2f(hB.z), acc[2]);
        acc[3] = fmaf(pB, bf2f(hB.w), acc[3]);
        acc[0] = fmaf(pC, bf2f(hC.x), acc[0]);
        acc[1] = fmaf(pC, bf2f(hC.y), acc[1]);
        acc[2] = fmaf(pC, bf2f(hC.z), acc[2]);
        acc[3] = fmaf(pC, bf2f(hC.w), acc[3]);
        acc[0] = fmaf(pD, bf2f(hD.x), acc[0]);
        acc[1] = fmaf(pD, bf2f(hD.y), acc[1]);
        acc[2] = fmaf(pD, bf2f(hD.z), acc[2]);
        acc[3] = fmaf(pD, bf2f(hD.w), acc[3]);
    }
    for (; i < e_n; ++i) {
        int cA = colS[i];
        ushort4 hA = *(const ushort4*)&h1[(size_t)cA * 64 + c4 * 4];
        float pA = pS[i * 4 + head];
        den += pA;
        acc[0] = fmaf(pA, bf2f(hA.x), acc[0]);
        acc[1] = fmaf(pA, bf2f(hA.y), acc[1]);
        acc[2] = fmaf(pA, bf2f(hA.z), acc[2]);
        acc[3] = fmaf(pA, bf2f(hA.w), acc[3]);
    }
    {
        float inv = 1.f / (den + 1e-16f);
        ushort4 zv;
        zv.x = f2bf(relu_np(acc[0] * inv + bS[c4 * 4 + 0]));
        zv.y = f2bf(relu_np(acc[1] * inv + bS[c4 * 4 + 1]));
        zv.z = f2bf(relu_np(acc[2] * inv + bS[c4 * 4 + 2]));
        zv.w = f2bf(relu_np(acc[3] * inv + bS[c4 * 4 + 3]));
        *(ushort4*)&zS[nb * 72 + c4 * 4] = zv;
    }
    __syncthreads();

    const int m = c4, quad = g;
    for (int t = w; t < 5; t += 4) {
        f32x4 acct = {0, 0, 0, 0};
        #pragma unroll
        for (int ks = 0; ks < 64; ks += 32) {
            short8 a = *(const short8*)&zS[m * 72 + ks + quad * 8];
            short8 b = *(const short8*)&wExt[(t * 16 + m) * 64 + ks + quad * 8];
            acct = __builtin_amdgcn_mfma_f32_16x16x32_bf16(a, b, acct, 0, 0, 0);
        }
        if (t < 4) {
            #pragma unroll
            for (int r = 0; r < 4; ++r)
                h2[(size_t)(n0 + quad * 4 + r) * 64 + t * 16 + m] = f2bf(acct[r]);
        } else {
            #pragma unroll
            for (int r = 0; r < 4; ++r) {
                int row = n0 + quad * 4 + r;
                if (m == 0) as2[row] = acct[r];
                else if (m == 1) ad2[row] = acct[r];
            }
        }
    }
}

// ---------------- layer-2 seg aggregation + fused classifier head -----------
__global__ __launch_bounds__(256, 8) void k_seg2f(
    const int* __restrict__ rp, const uchar* __restrict__ rcnt,
    const int* __restrict__ col,
    const float* __restrict__ as2, const float* __restrict__ ad2,
    const ushort* __restrict__ h2, const float* __restrict__ b2,
    const float* __restrict__ Wc, const float* __restrict__ bc,
    float* __restrict__ out)
{
    __shared__ float pS[CHE];
    __shared__ int colS[CHE];
    __shared__ uchar ndS[CHE];
    __shared__ int sRp[BN + 1];
    __shared__ float adS[BN];
    __shared__ float b2S[64];
    __shared__ float wcS[64];

    const int tid = threadIdx.x;
    const int n0 = blockIdx.x * BN;
    if (tid < 64) { b2S[tid] = b2[tid]; wcS[tid] = Wc[tid]; }
    if (tid < BN) { sRp[tid] = rp[n0 + tid]; adS[tid] = ad2[n0 + tid]; }
    if (tid == BN) sRp[BN] = rp[n0 + BN - 1] + (int)rcnt[n0 + BN - 1];
    __syncthreads();

    const int eb0 = sRp[0];
    const int cnt = min(sRp[BN] - eb0, CHE);
    for (int t = tid; t < cnt; t += 256) {
        int ge = eb0 + t;
        colS[t] = col[ge];
        int nd = 0;
        #pragma unroll
        for (int k = 1; k < BN; ++k) nd += (ge >= sRp[k]);
        ndS[t] = (uchar)nd;
    }
    __syncthreads();
    for (int t = tid; t < cnt; t += 256)
        pS[t] = __expf(lrelu(as2[colS[t]] + adS[ndS[t]]));
    __syncthreads();

    const int w = tid >> 6, lane = tid & 63;
    const int g = lane >> 4, c4 = lane & 15;
    const int nb = w * 4 + g;
    const int myn = n0 + nb;
    const int s_n = sRp[nb] - eb0, e_n = sRp[nb + 1] - eb0;

    f32x4 acc = {0, 0, 0, 0};
    float den = 0.f;
    int i = s_n;
    for (; i + 3 < e_n; i += 4) {
        int cA = colS[i], cB = colS[i + 1], cC = colS[i + 2], cD = colS[i + 3];
        ushort4 hA = *(const ushort4*)&h2[(size_t)cA * 64 + c4 * 4];
        ushort4 hB = *(const ushort4*)&h2[(size_t)cB * 64 + c4 * 4];
        ushort4 hC = *(const ushort4*)&h2[(size_t)cC * 64 + c4 * 4];
        ushort4 hD = *(const ushort4*)&h2[(size_t)cD * 64 + c4 * 4];
        float pA = pS[i + 0], pB = pS[i + 1], pC = pS[i + 2], pD = pS[i + 3];
        den += (pA + pB) + (pC + pD);
        acc[0] = fmaf(pA, bf2f(hA.x), acc[0]);
        acc[1] = fmaf(pA, bf2f(hA.y), acc[1]);
        acc[2] = fmaf(pA, bf2f(hA.z), acc[2]);
        acc[3] = fmaf(pA, bf2f(hA.w), acc[3]);
        acc[0] = fmaf(pB, bf2f(hB.x), acc[0]);
        acc[1] = fmaf(pB, bf2f(hB.y), acc[1]);
        acc[2] = fmaf(pB, bf2f(hB.z), acc[2]);
        acc[3] = fmaf(pB, bf2f(hB.w), acc[3]);
        acc[0] = fmaf(pC, bf2f(hC.x), acc[0]);
        acc[1] = fmaf(pC, bf2f(hC.y), acc[1]);
        acc[2] = fmaf(pC, bf2f(hC.z), acc[2]);
        acc[3] = fmaf(pC, bf2f(hC.w), acc[3]);
        acc[0] = fmaf(pD, bf2f(hD.x), acc[0]);
        acc[1] = fmaf(pD, bf2f(hD.y), acc[1]);
        acc[2] = fmaf(pD, bf2f(hD.z), acc[2]);
        acc[3] = fmaf(pD, bf2f(hD.w), acc[3]);
    }
    for (; i < e_n; ++i) {
        int cA = colS[i];
        ushort4 hA = *(const ushort4*)&h2[(size_t)cA * 64 + c4 * 4];
        float pA = pS[i];
        den += pA;
        acc[0] = fmaf(pA, bf2f(hA.x), acc[0]);
        acc[1] = fmaf(pA, bf2f(hA.y), acc[1]);
        acc[2] = fmaf(pA, bf2f(hA.z), acc[2]);
        acc[3] = fmaf(pA, bf2f(hA.w), acc[3]);
    }

    float inv = 1.f / (den + 1e-16f);
    float t2 = 0.f;
    #pragma unroll
    for (int j = 0; j < 4; ++j)
        t2 += relu_np(acc[j] * inv + b2S[c4 * 4 + j]) * wcS[c4 * 4 + j];
    t2 += __shfl_xor(t2, 1);
    t2 += __shfl_xor(t2, 2);
    t2 += __shfl_xor(t2, 4);
    t2 += __shfl_xor(t2, 8);
    if (c4 == 0) out[myn] = t2 + bc[0];
}

extern "C" void kernel_launch(void* const* d_in, const int* in_sizes, int n_in,
                              void* d_out, int out_size, void* d_ws, size_t ws_size,
                              hipStream_t stream)
{
    const float* x   = (const float*)d_in[0];
    const int*   ei  = (const int*)d_in[1];
    const float* W1  = (const float*)d_in[2];
    const float* aS1 = (const float*)d_in[3];
    const float* aD1 = (const float*)d_in[4];
    const float* b1  = (const float*)d_in[5];
    const float* W2  = (const float*)d_in[6];
    const float* aS2 = (const float*)d_in[7];
    const float* aD2 = (const float*)d_in[8];
    const float* b2  = (const float*)d_in[9];
    const float* Wc  = (const float*)d_in[10];
    const float* bc  = (const float*)d_in[11];
    float* out = (float*)d_out;

    const int* src = ei;
    const int* dst = ei + EE;

    // ---- workspace layout (~38 MB) ----
    ushort* h1   = (ushort*)d_ws;                     // [N*64] bf16  12.8MB
    ushort* h2   = h1 + (size_t)NN * 64;              // [N*64] bf16  12.8MB
    float*  as1  = (float*)(h2 + (size_t)NN * 64);    // [4N]
    float*  ad1  = as1 + (size_t)NN * 4;              // [4N]
    float*  as2  = ad1 + (size_t)NN * 4;              // [N]
    float*  ad2  = as2 + (size_t)NN;                  // [N]
    ushort* wExt = (ushort*)(ad2 + (size_t)NN);       // [80*64] bf16 10KB
    ushort* wB16 = wExt + 80 * 64;                    // [64*128] bf16 16KB
    ushort* wE16 = wB16 + 64 * 128;                   // [16*128] bf16 4KB
    int* row_ptr = (int*)(wE16 + 16 * 128);           // [N]
    uchar* rcnt  = (uchar*)(row_ptr + NN);            // [N] bytes
    int* gcur    = (int*)(rcnt + ((NN + 3) & ~3));    // [NBK] relative counts
    int* col     = gcur + NBK;                        // [NBK*CAP] 8MB arena
    int* pairs   = (int*)h2;                          // aliases h2 (dead by seg1)

    // ---- stage 0: zero bucket counters (784 B DMA node) ----
    hipMemsetAsync(gcur, 0, NBK * sizeof(int), stream);

    // ---- stage 1: part || weight-table build ----
    k_pt<<<NT + 2, 256, 0, stream>>>(src, dst, gcur, pairs,
                                     W1, aS1, aD1, W2, aS2, aD2,
                                     wB16, wE16, wExt);

    // ---- stage 2: bucket CSR finalize || gemm1 (global-B) ----
    k_bgg<<<NBK + GP, 256, 0, stream>>>(gcur, pairs, row_ptr, rcnt, col,
                                        x, wB16, wE16, h1, as1, ad1);

    // ---- stage 3: layer 1 aggregation + fused layer 2 GEMM ----
    k_seg1f<<<NGRP, 256, 0, stream>>>(row_ptr, rcnt, col, as1, ad1, h1, b1,
                                      wExt, h2, as2, ad2);

    // ---- stage 4: layer 2 aggregation + fused classifier ----
    k_seg2f<<<NGRP, 256, 0, stream>>>(row_ptr, rcnt, col, as2, ad2, h2,
                                      b2, Wc, bc, out);
}